// Round 1
// baseline (1001.475 us; speedup 1.0000x reference)
//
#include <hip/hip_runtime.h>
#include <hip/hip_bf16.h>
#include <cmath>

// Problem: CPL_MoE  B=32, L=64, H=1024, E=8, K=2, V=12000, OUT=16
#define B_   32
#define L_   64
#define H_   1024
#define E_   8
#define V_   12000
#define OUT_ 16
#define HID_ 512

#define BN  96   // v-tile per block (125 tiles * 96 = 12000 exactly)
#define BK  64   // k-tile
#define LDK 72   // padded LDS row stride in bf16 elems (144 B = 36 banks -> 2-way max, free)

#define COMP_OFF 512                      // d_out: [0,512) gauss_param
#define LOSS_OFF (512 + B_ * L_ * V_)     // last element: moe_loss

using f32x4  = __attribute__((ext_vector_type(4))) float;
using bf16x8 = __attribute__((ext_vector_type(8))) short;
using s16x4  = __attribute__((ext_vector_type(4))) short;

__device__ __forceinline__ short f2bf(float f) {
  unsigned u = __builtin_bit_cast(unsigned, f);
  u = (u + 0x7FFFu + ((u >> 16) & 1u)) >> 16;   // round-to-nearest-even
  return (short)u;
}

// ---------------------------------------------------------------------------
// Kernel 1: gating. One block per batch row.
// hid = relu(q @ W1 + b1); logits = hid @ W2 + b2; top-2 softmax.
// Writes gates[B][E] (dense, for importance), egate[B][2], eidx[B][2].
// ---------------------------------------------------------------------------
__global__ __launch_bounds__(256) void k_gate(
    const float* __restrict__ q,  const float* __restrict__ w1,
    const float* __restrict__ b1, const float* __restrict__ w2,
    const float* __restrict__ b2, float* __restrict__ gates,
    float* __restrict__ egate,    int* __restrict__ eidx) {
  __shared__ __align__(16) float qs[H_];
  __shared__ __align__(16) float hid[HID_];
  __shared__ __align__(16) float red[256][8];
  const int t = threadIdx.x;
  const int b = blockIdx.x;

  ((f32x4*)qs)[t] = ((const f32x4*)(q + (size_t)b * H_))[t];
  __syncthreads();

  // hid: thread -> 4 consecutive j's (jq = t&127), i-range halved (ih = t>>7)
  {
    const int jq = t & 127, ih = t >> 7;
    f32x4 acc = {0.f, 0.f, 0.f, 0.f};
    const float* wp = w1 + (size_t)(ih * 512) * HID_ + 4 * jq;
    for (int i = 0; i < 512; ++i) {
      acc += qs[ih * 512 + i] * *(const f32x4*)(wp + (size_t)i * HID_);
    }
    *(f32x4*)&red[t][0] = acc;
  }
  __syncthreads();
  if (t < 128) {
    f32x4 a = *(f32x4*)&red[t][0];
    a += *(f32x4*)&red[t + 128][0];
    a += *(const f32x4*)(b1 + 4 * t);
    f32x4 r;
    #pragma unroll
    for (int c = 0; c < 4; ++c) r[c] = fmaxf(a[c], 0.f);
    *(f32x4*)&hid[4 * t] = r;
  }
  __syncthreads();

  // logits partials: thread t covers j = t and j = t+256
  {
    const float h0 = hid[t], h1 = hid[t + 256];
    const float* w2a = w2 + (size_t)t * E_;
    const float* w2b = w2 + (size_t)(t + 256) * E_;
    #pragma unroll
    for (int e = 0; e < 8; ++e) red[t][e] = h0 * w2a[e] + h1 * w2b[e];
  }
  __syncthreads();
  for (int s = 128; s > 0; s >>= 1) {
    if (t < s) {
      #pragma unroll
      for (int e = 0; e < 8; ++e) red[t][e] += red[t + s][e];
    }
    __syncthreads();
  }

  if (t == 0) {
    float lg[8];
    #pragma unroll
    for (int e = 0; e < 8; ++e) lg[e] = red[0][e] + b2[e];
    int e1 = 0;
    #pragma unroll
    for (int e = 1; e < 8; ++e) if (lg[e] > lg[e1]) e1 = e;     // lowest idx wins ties
    int e2 = (e1 == 0) ? 1 : 0;
    #pragma unroll
    for (int e = 0; e < 8; ++e) if (e != e1 && lg[e] > lg[e2]) e2 = e;
    const float x2 = expf(lg[e2] - lg[e1]);   // softmax over [lg[e1], lg[e2]]
    const float g1 = 1.f / (1.f + x2);
    const float g2 = x2 / (1.f + x2);
    #pragma unroll
    for (int e = 0; e < 8; ++e)
      gates[b * E_ + e] = (e == e1) ? g1 : (e == e2) ? g2 : 0.f;
    egate[2 * b] = g1; egate[2 * b + 1] = g2;
    eidx[2 * b]  = e1; eidx[2 * b + 1]  = e2;
  }
}

// ---------------------------------------------------------------------------
// Kernel 2: moe_loss + gauss_param. One block, 512 threads (thread = (b,o)).
// ---------------------------------------------------------------------------
__global__ __launch_bounds__(512) void k_small(
    const float* __restrict__ h,     const float* __restrict__ gw,
    const float* __restrict__ gb,    const float* __restrict__ gates,
    const float* __restrict__ egate, const int* __restrict__ eidx,
    float* __restrict__ out) {
  __shared__ float imp[8];
  const int t = threadIdx.x;

  if (t < 8) {
    float s = 0.f;
    for (int b = 0; b < B_; ++b) s += gates[b * E_ + t];
    imp[t] = s;
  }
  __syncthreads();
  if (t == 0) {
    float m = 0.f;
    #pragma unroll
    for (int e = 0; e < 8; ++e) m += imp[e];
    m *= 0.125f;
    float var = 0.f;
    #pragma unroll
    for (int e = 0; e < 8; ++e) { const float d = imp[e] - m; var += d * d; }
    var *= (1.f / 7.f);                                  // ddof=1
    out[LOSS_OFF] = sqrtf(var) / (m + 1e-10f) * 0.1f;
  }

  // gauss_param: sigmoid(h_last[b] . (g1*gw[e1,o]+g2*gw[e2,o]) + mixed bias)
  const int b = t >> 4, o = t & 15;
  const int e1 = eidx[2 * b], e2 = eidx[2 * b + 1];
  const float g1 = egate[2 * b], g2 = egate[2 * b + 1];
  const float* hl = h + ((size_t)(b * L_ + (L_ - 1))) * H_;
  const float* wa = gw + ((size_t)(e1 * OUT_ + o)) * H_;
  const float* wb = gw + ((size_t)(e2 * OUT_ + o)) * H_;
  float acc = g1 * gb[e1 * OUT_ + o] + g2 * gb[e2 * OUT_ + o];
  for (int i = 0; i < H_; i += 4) {
    const f32x4 hv = *(const f32x4*)(hl + i);
    const f32x4 va = *(const f32x4*)(wa + i);
    const f32x4 vb = *(const f32x4*)(wb + i);
    const f32x4 w  = g1 * va + g2 * vb;
    acc += hv[0] * w[0] + hv[1] * w[1] + hv[2] * w[2] + hv[3] * w[3];
  }
  out[t] = 1.f / (1.f + expf(-acc));   // t == b*16+o
}

// ---------------------------------------------------------------------------
// Kernel 3: comp. Block = (batch b, v-tile). M=64 (all L), N=96, K-loop H.
// Mix the two selected experts' fp32 weights -> bf16 in staging, then
// 16x16x32 bf16 MFMA. blockIdx.x = b (fast) so blocks sharing a v-tile run
// concurrently -> expert-slice reuse hits L2/LLC.
// ---------------------------------------------------------------------------
__global__ __launch_bounds__(256) void k_comp(
    const float* __restrict__ h,     const float* __restrict__ cw,
    const float* __restrict__ cb,    const float* __restrict__ egate,
    const int* __restrict__ eidx,    float* __restrict__ out) {
  __shared__ __align__(16) short As[L_ * LDK];   // h tile, bf16
  __shared__ __align__(16) short Bs[BN * LDK];   // mixed weight tile, bf16
  const int t  = threadIdx.x;
  const int b  = blockIdx.x;
  const int vt = blockIdx.y;
  const int e1 = eidx[2 * b], e2 = eidx[2 * b + 1];
  const float g1 = egate[2 * b], g2 = egate[2 * b + 1];

  const float* hrow = h + ((size_t)b * L_ + (t >> 2)) * H_ + ((t & 3) * 16);
  const float* w1p  = cw + ((size_t)e1 * V_ + (size_t)vt * BN) * H_;
  const float* w2p  = cw + ((size_t)e2 * V_ + (size_t)vt * BN) * H_;

  f32x4 acc[6];
  #pragma unroll
  for (int i = 0; i < 6; ++i) acc[i] = (f32x4){0.f, 0.f, 0.f, 0.f};

  const int wv = t >> 6;           // wave 0..3 -> M-stripe of 16 rows
  const int lane = t & 63;
  const int lr = lane & 15, quad = lane >> 4;
  const short* Ap = As + (wv * 16 + lr) * LDK;
  const short* Bp = Bs + lr * LDK;

  const int wr = t >> 3;           // weight staging: 32 rows/pass
  const int wc = (t & 7) * 8;      // 8 cols per thread

  for (int k0 = 0; k0 < H_; k0 += BK) {
    // stage h: row = t>>2, 16 cols at (t&3)*16
    {
      const float* src = hrow + k0;
      short* dst = As + (t >> 2) * LDK + (t & 3) * 16;
      #pragma unroll
      for (int c = 0; c < 16; c += 4) {
        const f32x4 v = *(const f32x4*)(src + c);
        s16x4 sv;
        sv[0] = f2bf(v[0]); sv[1] = f2bf(v[1]);
        sv[2] = f2bf(v[2]); sv[3] = f2bf(v[3]);
        *(s16x4*)(dst + c) = sv;
      }
    }
    // stage mixed weights: 3 passes x 32 rows
    #pragma unroll
    for (int p = 0; p < 3; ++p) {
      const int r = p * 32 + wr;
      const float* s1 = w1p + (size_t)r * H_ + k0 + wc;
      const float* s2 = w2p + (size_t)r * H_ + k0 + wc;
      short* dst = Bs + r * LDK + wc;
      #pragma unroll
      for (int c = 0; c < 8; c += 4) {
        const f32x4 a  = *(const f32x4*)(s1 + c);
        const f32x4 bb = *(const f32x4*)(s2 + c);
        const f32x4 m  = g1 * a + g2 * bb;
        s16x4 sv;
        sv[0] = f2bf(m[0]); sv[1] = f2bf(m[1]);
        sv[2] = f2bf(m[2]); sv[3] = f2bf(m[3]);
        *(s16x4*)(dst + c) = sv;
      }
    }
    __syncthreads();

    #pragma unroll
    for (int ks = 0; ks < BK; ks += 32) {
      const bf16x8 af = *(const bf16x8*)(Ap + ks + quad * 8);
      #pragma unroll
      for (int n = 0; n < 6; ++n) {
        const bf16x8 bf = *(const bf16x8*)(Bp + n * 16 * LDK + ks + quad * 8);
        acc[n] = __builtin_amdgcn_mfma_f32_16x16x32_bf16(af, bf, acc[n], 0, 0, 0);
      }
    }
    __syncthreads();
  }

  // epilogue: mixed bias + store (D layout: col=lane&15, row=quad*4+r)
  #pragma unroll
  for (int n = 0; n < 6; ++n) {
    const int v = vt * BN + n * 16 + lr;
    const float bias = g1 * cb[e1 * V_ + v] + g2 * cb[e2 * V_ + v];
    #pragma unroll
    for (int r = 0; r < 4; ++r) {
      const int l = wv * 16 + quad * 4 + r;
      out[COMP_OFF + ((size_t)(b * L_ + l)) * V_ + v] = acc[n][r] + bias;
    }
  }
}

// ---------------------------------------------------------------------------
extern "C" void kernel_launch(void* const* d_in, const int* in_sizes, int n_in,
                              void* d_out, int out_size, void* d_ws, size_t ws_size,
                              hipStream_t stream) {
  const float* q   = (const float*)d_in[0];
  const float* h   = (const float*)d_in[1];
  const float* w1  = (const float*)d_in[2];
  const float* b1  = (const float*)d_in[3];
  const float* w2  = (const float*)d_in[4];
  const float* b2  = (const float*)d_in[5];
  const float* gw  = (const float*)d_in[6];
  const float* gb  = (const float*)d_in[7];
  const float* cw  = (const float*)d_in[8];
  const float* cbp = (const float*)d_in[9];
  float* out = (float*)d_out;

  // ws layout (floats): [0,256) gates[B][E]; [256,320) egate[B][2];
  // [320,384) eidx[B][2] as int. 1536 B total.
  float* F     = (float*)d_ws;
  float* gates = F;
  float* egate = F + 256;
  int*   eidx  = (int*)(F + 320);

  k_gate<<<B_, 256, 0, stream>>>(q, w1, b1, w2, b2, gates, egate, eidx);
  k_small<<<1, 512, 0, stream>>>(h, gw, gb, gates, egate, eidx, out);
  k_comp<<<dim3(B_, V_ / BN), 256, 0, stream>>>(h, cw, cbp, egate, eidx, out);
}